// Round 3
// baseline (56.904 us; speedup 1.0000x reference)
//
#include <hip/hip_runtime.h>
#include <stdint.h>

// Problem constants
#define BB 1024
#define MM 128
#define KK 32
#define NEDGE (BB * MM * KK)   // 4194304
#define BPB 4                  // blocks per batch
#define ROWS_PER_WAVE (MM / (4 * BPB))  // 8

typedef unsigned int uint2v __attribute__((ext_vector_type(2)));

// keep-min lane masks for the bitonic stages (compile-time)
static constexpr unsigned long long p1mask(int size, int stride) {
    unsigned long long m = 0;
    for (int l = 0; l < 64; ++l) {
        int g = l & 31;
        bool up = (((g & size) == 0) != (l >= 32));   // lower half asc, upper half desc
        bool keep = (((g & stride) == 0) == up);
        if (keep) m |= 1ull << l;
    }
    return m;
}
static constexpr unsigned long long cleanmask(int stride) {
    unsigned long long m = 0;
    for (int l = 0; l < 64; ++l) {
        int g = l & 31;
        if ((g & stride) == 0) m |= 1ull << l;
    }
    return m;
}

// partner fetch: DPP (VALU) for strides 1,2,8; ds_swizzle for 4,16
template<int STRIDE>
static __device__ __forceinline__ unsigned partner(unsigned k) {
#if __has_builtin(__builtin_amdgcn_update_dpp)
    if constexpr (STRIDE == 1)
        return (unsigned)__builtin_amdgcn_update_dpp((int)k, (int)k, 0xB1, 0xF, 0xF, false); // quad_perm [1,0,3,2]
    else if constexpr (STRIDE == 2)
        return (unsigned)__builtin_amdgcn_update_dpp((int)k, (int)k, 0x4E, 0xF, 0xF, false); // quad_perm [2,3,0,1]
    else if constexpr (STRIDE == 8)
        return (unsigned)__builtin_amdgcn_update_dpp((int)k, (int)k, 0x128, 0xF, 0xF, false); // row_ror:8 == xor8
    else
        return (unsigned)__builtin_amdgcn_ds_swizzle((int)k, (STRIDE << 10) | 0x1F);
#else
    return (unsigned)__builtin_amdgcn_ds_swizzle((int)k, (STRIDE << 10) | 0x1F);
#endif
}

// compare-exchange: partner + min + max + cndmask(const 64-bit SGPR lane mask)
template<int STRIDE, unsigned long long KEEPMIN>
static __device__ __forceinline__ unsigned cex(unsigned k) {
    unsigned p = partner<STRIDE>(k);
    unsigned mn = k < p ? k : p;
    unsigned mx = k < p ? p : k;
    unsigned r;
    asm("v_cndmask_b32 %0, %1, %2, %3" : "=v"(r) : "v"(mx), "v"(mn), "s"(KEEPMIN));
    return r;
}

// min over {k[i], k[i^32]} — bitonic split across the 32-lane halves
static __device__ __forceinline__ unsigned minxor32(unsigned k) {
#if __has_builtin(__builtin_amdgcn_permlane32_swap)
    uint2v s = __builtin_amdgcn_permlane32_swap(k, k, false, false);
    return s.x < s.y ? s.x : s.y;
#else
    unsigned p = (unsigned)__shfl_xor((int)k, 32, 64);
    return k < p ? k : p;
#endif
}

// grid = BB*BPB blocks of 256 threads; each wave handles 8 rows.
// Per row: 128 candidate keys (2/lane), packed key = (f32bits(d2) & ~0x7F) | j.
// Top-32: sort four 32-blocks, bitonic-split merge, clean, in-lane split, clean.
__global__ __launch_bounds__(256, 8) void knn_edges_kernel(const float* __restrict__ pos,
                                                           float* __restrict__ out) {
    __shared__ float4 pts[MM];   // {x, y, z, |p|^2}
    const int blk = blockIdx.x;
    const int b = blk >> 2;            // blk / BPB
    const int sub = blk & (BPB - 1);
    const int tid = threadIdx.x;

    if (tid < MM) {
        const float* p = pos + (size_t)(b * MM + tid) * 3;
        float x = p[0], y = p[1], z = p[2];
        float sq = __fadd_rn(__fadd_rn(__fmul_rn(x, x), __fmul_rn(y, y)), __fmul_rn(z, z));
        pts[tid] = make_float4(x, y, z, sq);
    }
    __syncthreads();

    const int wave = tid >> 6;
    const int lane = tid & 63;

    // per-lane candidate coordinates, hoisted across the row loop
    const int j0 = lane, j1 = lane + 64;
    const float4 pa = pts[j0];
    const float4 pb = pts[j1];

    const int row0 = sub * (MM / BPB) + wave * ROWS_PER_WAVE;

#pragma unroll 2
    for (int i = row0; i < row0 + ROWS_PER_WAVE; ++i) {
        const float4 pi = pts[i];
        const float xi = pi.x, yi = pi.y, zi = pi.z, qi = pi.w;

        // ---- candidate keys ----
        float dot0 = __fadd_rn(__fadd_rn(__fmul_rn(xi, pa.x), __fmul_rn(yi, pa.y)), __fmul_rn(zi, pa.z));
        float d20 = fmaxf(__fsub_rn(__fadd_rn(qi, pa.w), __fmul_rn(2.0f, dot0)), 0.0f);
        unsigned bits0 = (d20 < 25.0f) ? __float_as_uint(d20) : 0x7F800000u;
        unsigned k0 = (bits0 & 0xFFFFFF80u) | (unsigned)j0;

        float dot1 = __fadd_rn(__fadd_rn(__fmul_rn(xi, pb.x), __fmul_rn(yi, pb.y)), __fmul_rn(zi, pb.z));
        float d21 = fmaxf(__fsub_rn(__fadd_rn(qi, pb.w), __fmul_rn(2.0f, dot1)), 0.0f);
        unsigned bits1 = (d21 < 25.0f) ? __float_as_uint(d21) : 0x7F800000u;
        unsigned k1 = (bits1 & 0xFFFFFF80u) | (unsigned)j1;

        // ---- phase 1: sort the four 32-blocks (lower lanes asc, upper desc) ----
#define P1(S, ST) k0 = cex<ST, p1mask(S, ST)>(k0); k1 = cex<ST, p1mask(S, ST)>(k1);
        P1(2, 1)
        P1(4, 2)  P1(4, 1)
        P1(8, 4)  P1(8, 2)  P1(8, 1)
        P1(16, 8) P1(16, 4) P1(16, 2) P1(16, 1)
        P1(32, 16) P1(32, 8) P1(32, 4) P1(32, 2) P1(32, 1)
#undef P1

        // ---- phase 2: bitonic split across the 32-lane halves ----
        unsigned c  = minxor32(k0);   // smallest 32 of candidates 0..63   (bitonic)
        unsigned c2 = minxor32(k1);   // smallest 32 of candidates 64..127 (bitonic)

        // ---- phase 3: clean c ascending, c2 descending ----
#define P3(ST) c = cex<ST, cleanmask(ST)>(c); c2 = cex<ST, ~cleanmask(ST)>(c2);
        P3(16) P3(8) P3(4) P3(2) P3(1)
#undef P3

        // ---- phase 4: in-lane split of [c asc ; c2 desc] ----
        unsigned m = c < c2 ? c : c2;   // smallest 32 overall (bitonic)

        // ---- phase 5: final clean ascending ----
#define P5(ST) m = cex<ST, cleanmask(ST)>(m);
        P5(16) P5(8) P5(4) P5(2) P5(1)
#undef P5

        // ---- epilogue: rank r = lane&31, duplicated across halves ----
        const int r = lane & 31;
        const unsigned key = m;
        const bool taken = (key & 0xFFFFFF80u) != 0x7F800000u;
        const int j = (int)(key & 127u);
        const int sel = taken ? j : i;

        const float4 ps = pts[sel];
        float dxv = __fsub_rn(ps.x, xi);
        float dyv = __fsub_rn(ps.y, yi);
        float dzv = __fsub_rn(ps.z, zi);
        float w = 0.0f;
        if (taken && sel != i) {
            w = sqrtf(__fadd_rn(__fadd_rn(__fmul_rn(dxv, dxv), __fmul_rn(dyv, dyv)),
                                __fmul_rn(dzv, dzv)));
        }

        const int node = b * MM + i;
        const int e = node * KK + r;
        float* vec = out + 3 * (size_t)NEDGE + (size_t)e * 3;
        if (lane < 32) {
            out[e] = (float)(b * MM + sel);            // src
            vec[0] = dxv;
            vec[1] = dyv;
        } else {
            out[NEDGE + e] = (float)node;              // dst
            out[2 * (size_t)NEDGE + e] = w;            // weight
            vec[2] = dzv;
        }
    }
}

extern "C" void kernel_launch(void* const* d_in, const int* in_sizes, int n_in,
                              void* d_out, int out_size, void* d_ws, size_t ws_size,
                              hipStream_t stream) {
    const float* pos = (const float*)d_in[0];
    float* out = (float*)d_out;
    hipLaunchKernelGGL(knn_edges_kernel, dim3(BB * BPB), dim3(256), 0, stream, pos, out);
}

// Round 4
// 49.501 us; speedup vs baseline: 1.1496x; 1.1496x over previous
//
#include <hip/hip_runtime.h>
#include <stdint.h>

// Problem constants
#define BB 1024
#define MM 128
#define KK 32
#define NEDGE (BB * MM * KK)   // 4194304
#define BPB 4                  // blocks per batch
#define ROWS_PER_WAVE (MM / (4 * BPB))  // 8

typedef unsigned int uint2v __attribute__((ext_vector_type(2)));

// keep-min lane masks for the bitonic stages (compile-time)
static constexpr unsigned long long p1mask(int size, int stride) {
    unsigned long long m = 0;
    for (int l = 0; l < 64; ++l) {
        int g = l & 31;
        bool up = (((g & size) == 0) != (l >= 32));   // lower half asc, upper half desc
        bool keep = (((g & stride) == 0) == up);
        if (keep) m |= 1ull << l;
    }
    return m;
}
static constexpr unsigned long long cleanmask(int stride) {
    unsigned long long m = 0;
    for (int l = 0; l < 64; ++l) {
        int g = l & 31;
        if ((g & stride) == 0) m |= 1ull << l;
    }
    return m;
}

// compare-exchange, 3 VALU each:
//  strides 1,2,8 : v_min_u32_dpp / v_max_u32_dpp (DPP fused on consumer) + cndmask
//  strides 4,16  : ds_swizzle partner (LDS pipe) + v_min/v_max + cndmask
template<int ST, unsigned long long MASK>
static __device__ __forceinline__ unsigned cex(unsigned k) {
    unsigned mn, mx, r;
    if constexpr (ST == 1) {
        asm("s_nop 1\n\t"
            "v_min_u32_dpp %0, %2, %2 quad_perm:[1,0,3,2] row_mask:0xf bank_mask:0xf\n\t"
            "v_max_u32_dpp %1, %2, %2 quad_perm:[1,0,3,2] row_mask:0xf bank_mask:0xf"
            : "=&v"(mn), "=&v"(mx) : "v"(k));
    } else if constexpr (ST == 2) {
        asm("s_nop 1\n\t"
            "v_min_u32_dpp %0, %2, %2 quad_perm:[2,3,0,1] row_mask:0xf bank_mask:0xf\n\t"
            "v_max_u32_dpp %1, %2, %2 quad_perm:[2,3,0,1] row_mask:0xf bank_mask:0xf"
            : "=&v"(mn), "=&v"(mx) : "v"(k));
    } else if constexpr (ST == 8) {
        asm("s_nop 1\n\t"
            "v_min_u32_dpp %0, %2, %2 row_ror:8 row_mask:0xf bank_mask:0xf\n\t"
            "v_max_u32_dpp %1, %2, %2 row_ror:8 row_mask:0xf bank_mask:0xf"
            : "=&v"(mn), "=&v"(mx) : "v"(k));
    } else {
        unsigned p = (unsigned)__builtin_amdgcn_ds_swizzle((int)k, (ST << 10) | 0x1F);
        mn = __builtin_elementwise_min(k, p);
        mx = __builtin_elementwise_max(k, p);
    }
    asm("v_cndmask_b32 %0, %1, %2, %3" : "=v"(r) : "v"(mx), "v"(mn), "s"(MASK));
    return r;
}

// min over {k[i], k[i^32]} — bitonic split across the 32-lane halves
static __device__ __forceinline__ unsigned minxor32(unsigned k) {
#if __has_builtin(__builtin_amdgcn_permlane32_swap)
    uint2v s = __builtin_amdgcn_permlane32_swap(k, k, false, false);
    return __builtin_elementwise_min(s.x, s.y);
#else
    unsigned p = (unsigned)__shfl_xor((int)k, 32, 64);
    return __builtin_elementwise_min(k, p);
#endif
}

// grid = BB*BPB blocks of 256 threads; each wave handles 8 rows.
// Per row: 128 candidate keys (2/lane), key = (f32bits(max(d2,0)) & ~0x7F) | j
// (no cutoff clamp: taken <=> key < f32bits(25.0), exact after masking).
// Top-32: sort four 32-blocks, bitonic-split merge, clean, in-lane split, clean.
__global__ __launch_bounds__(256, 8) void knn_edges_kernel(const float* __restrict__ pos,
                                                           float* __restrict__ out) {
    __shared__ float px[MM], py[MM], pz[MM], sqs[MM];
    const int blk = blockIdx.x;
    const int b = blk >> 2;            // blk / BPB
    const int sub = blk & (BPB - 1);
    const int tid = threadIdx.x;

    if (tid < MM) {
        const float* p = pos + (size_t)(b * MM + tid) * 3;
        float x = p[0], y = p[1], z = p[2];
        px[tid] = x; py[tid] = y; pz[tid] = z;
        sqs[tid] = __fadd_rn(__fadd_rn(__fmul_rn(x, x), __fmul_rn(y, y)), __fmul_rn(z, z));
    }
    __syncthreads();

    const int wave = tid >> 6;
    const int lane = tid & 63;

    // per-lane candidate coordinates, hoisted across the row loop
    const int j0 = lane, j1 = lane + 64;
    const float xa = px[j0], ya = py[j0], za = pz[j0], qa = sqs[j0];
    const float xb = px[j1], yb = py[j1], zb = pz[j1], qb = sqs[j1];

    const int row0 = sub * (MM / BPB) + wave * ROWS_PER_WAVE;

#pragma unroll 2
    for (int i = row0; i < row0 + ROWS_PER_WAVE; ++i) {
        const float xi = px[i], yi = py[i], zi = pz[i], qi = sqs[i];

        // ---- candidate keys (fma ok: ulp-level rank flips tolerated) ----
        float dot0 = fmaf(xi, xa, fmaf(yi, ya, zi * za));
        float d20 = fmaxf((qi + qa) - 2.0f * dot0, 0.0f);
        unsigned k0 = (__float_as_uint(d20) & 0xFFFFFF80u) | (unsigned)j0;

        float dot1 = fmaf(xi, xb, fmaf(yi, yb, zi * zb));
        float d21 = fmaxf((qi + qb) - 2.0f * dot1, 0.0f);
        unsigned k1 = (__float_as_uint(d21) & 0xFFFFFF80u) | (unsigned)j1;

        // ---- phase 1: sort the four 32-blocks (lower lanes asc, upper desc) ----
#define P1(S, ST) k0 = cex<ST, p1mask(S, ST)>(k0); k1 = cex<ST, p1mask(S, ST)>(k1);
        P1(2, 1)
        P1(4, 2)  P1(4, 1)
        P1(8, 4)  P1(8, 2)  P1(8, 1)
        P1(16, 8) P1(16, 4) P1(16, 2) P1(16, 1)
        P1(32, 16) P1(32, 8) P1(32, 4) P1(32, 2) P1(32, 1)
#undef P1

        // ---- phase 2: bitonic split across the 32-lane halves ----
        unsigned c  = minxor32(k0);   // smallest 32 of candidates 0..63   (bitonic)
        unsigned c2 = minxor32(k1);   // smallest 32 of candidates 64..127 (bitonic)

        // ---- phase 3: clean c ascending, c2 descending ----
#define P3(ST) c = cex<ST, cleanmask(ST)>(c); c2 = cex<ST, ~cleanmask(ST)>(c2);
        P3(16) P3(8) P3(4) P3(2) P3(1)
#undef P3

        // ---- phase 4: in-lane split of [c asc ; c2 desc] ----
        unsigned m = __builtin_elementwise_min(c, c2);   // smallest 32 overall (bitonic)

        // ---- phase 5: final clean ascending ----
#define P5(ST) m = cex<ST, cleanmask(ST)>(m);
        P5(16) P5(8) P5(4) P5(2) P5(1)
#undef P5

        // ---- epilogue: rank r = lane&31, duplicated across halves ----
        const int r = lane & 31;
        const bool taken = m < 0x41C80000u;   // d2 < 25.0
        const int j = (int)(m & 127u);
        const int sel = taken ? j : i;

        float dxv = __fsub_rn(px[sel], xi);
        float dyv = __fsub_rn(py[sel], yi);
        float dzv = __fsub_rn(pz[sel], zi);
        float w = 0.0f;
        if (taken && sel != i) {
            w = sqrtf(__fadd_rn(__fadd_rn(__fmul_rn(dxv, dxv), __fmul_rn(dyv, dyv)),
                                __fmul_rn(dzv, dzv)));
        }

        const int node = b * MM + i;
        const int e = node * KK + r;
        float* vec = out + 3 * (size_t)NEDGE + (size_t)e * 3;
        if (lane < 32) {
            out[e] = (float)(b * MM + sel);            // src
            vec[0] = dxv;
            vec[1] = dyv;
        } else {
            out[NEDGE + e] = (float)node;              // dst
            out[2 * (size_t)NEDGE + e] = w;            // weight
            vec[2] = dzv;
        }
    }
}

extern "C" void kernel_launch(void* const* d_in, const int* in_sizes, int n_in,
                              void* d_out, int out_size, void* d_ws, size_t ws_size,
                              hipStream_t stream) {
    const float* pos = (const float*)d_in[0];
    float* out = (float*)d_out;
    hipLaunchKernelGGL(knn_edges_kernel, dim3(BB * BPB), dim3(256), 0, stream, pos, out);
}

// Round 5
// 48.942 us; speedup vs baseline: 1.1627x; 1.0114x over previous
//
#include <hip/hip_runtime.h>
#include <stdint.h>

// Problem constants
#define BB 1024
#define MM 128
#define KK 32
#define NEDGE (BB * MM * KK)   // 4194304
#define BPB 4                  // blocks per batch
#define ROWS_PER_WAVE (MM / (4 * BPB))  // 8

typedef unsigned int uint2v __attribute__((ext_vector_type(2)));

// keep-min lane masks for the bitonic stages (compile-time)
static constexpr unsigned long long p1mask(int size, int stride) {
    unsigned long long m = 0;
    for (int l = 0; l < 64; ++l) {
        int g = l & 31;
        bool up = (((g & size) == 0) != (l >= 32));   // lower half asc, upper half desc
        bool keep = (((g & stride) == 0) == up);
        if (keep) m |= 1ull << l;
    }
    return m;
}
static constexpr unsigned long long cleanmask(int stride) {
    unsigned long long m = 0;
    for (int l = 0; l < 64; ++l) {
        int g = l & 31;
        if ((g & stride) == 0) m |= 1ull << l;
    }
    return m;
}

// compare-exchange, 3 VALU each:
//  strides 1,2,8 : v_min_u32_dpp / v_max_u32_dpp (DPP fused on consumer) + cndmask
//  strides 4,16  : ds_swizzle partner (LDS pipe) + v_min/v_max + cndmask
template<int ST, unsigned long long MASK>
static __device__ __forceinline__ unsigned cex(unsigned k) {
    unsigned mn, mx, r;
    if constexpr (ST == 1) {
        asm("s_nop 1\n\t"
            "v_min_u32_dpp %0, %2, %2 quad_perm:[1,0,3,2] row_mask:0xf bank_mask:0xf\n\t"
            "v_max_u32_dpp %1, %2, %2 quad_perm:[1,0,3,2] row_mask:0xf bank_mask:0xf"
            : "=&v"(mn), "=&v"(mx) : "v"(k));
    } else if constexpr (ST == 2) {
        asm("s_nop 1\n\t"
            "v_min_u32_dpp %0, %2, %2 quad_perm:[2,3,0,1] row_mask:0xf bank_mask:0xf\n\t"
            "v_max_u32_dpp %1, %2, %2 quad_perm:[2,3,0,1] row_mask:0xf bank_mask:0xf"
            : "=&v"(mn), "=&v"(mx) : "v"(k));
    } else if constexpr (ST == 8) {
        asm("s_nop 1\n\t"
            "v_min_u32_dpp %0, %2, %2 row_ror:8 row_mask:0xf bank_mask:0xf\n\t"
            "v_max_u32_dpp %1, %2, %2 row_ror:8 row_mask:0xf bank_mask:0xf"
            : "=&v"(mn), "=&v"(mx) : "v"(k));
    } else {
        unsigned p = (unsigned)__builtin_amdgcn_ds_swizzle((int)k, (ST << 10) | 0x1F);
        mn = __builtin_elementwise_min(k, p);
        mx = __builtin_elementwise_max(k, p);
    }
    asm("v_cndmask_b32 %0, %1, %2, %3" : "=v"(r) : "v"(mx), "v"(mn), "s"(MASK));
    return r;
}

// min over {k[i], k[i^32]} — bitonic split across the 32-lane halves
static __device__ __forceinline__ unsigned minxor32(unsigned k) {
#if __has_builtin(__builtin_amdgcn_permlane32_swap)
    uint2v s = __builtin_amdgcn_permlane32_swap(k, k, false, false);
    return __builtin_elementwise_min(s.x, s.y);
#else
    unsigned p = (unsigned)__shfl_xor((int)k, 32, 64);
    return __builtin_elementwise_min(k, p);
#endif
}

// grid = BB*BPB blocks of 256 threads; each wave handles 8 rows.
// Per row: 128 candidate keys (2/lane), key = (f32bits(max(d2,0)) & ~0x7F) | j
// (no cutoff clamp: taken <=> key < f32bits(25.0), exact after masking).
// Top-32: sort four 32-blocks, bitonic-split merge, clean, in-lane split, clean.
__global__ __launch_bounds__(256, 4) void knn_edges_kernel(const float* __restrict__ pos,
                                                           float* __restrict__ out) {
    __shared__ float px[MM], py[MM], pz[MM], sqs[MM];
    const int blk = blockIdx.x;
    const int b = blk >> 2;            // blk / BPB
    const int sub = blk & (BPB - 1);
    const int tid = threadIdx.x;

    if (tid < MM) {
        const float* p = pos + (size_t)(b * MM + tid) * 3;
        float x = p[0], y = p[1], z = p[2];
        px[tid] = x; py[tid] = y; pz[tid] = z;
        sqs[tid] = __fadd_rn(__fadd_rn(__fmul_rn(x, x), __fmul_rn(y, y)), __fmul_rn(z, z));
    }
    __syncthreads();

    const int wave = tid >> 6;
    const int lane = tid & 63;
    const int r = lane & 31;
    const bool hi = lane >= 32;

    // per-lane candidate coordinates, hoisted across the row loop
    const int j0 = lane, j1 = lane + 64;
    const float xa = px[j0], ya = py[j0], za = pz[j0], qa = sqs[j0];
    const float xb = px[j1], yb = py[j1], zb = pz[j1], qb = sqs[j1];

    const int row0 = sub * (MM / BPB) + wave * ROWS_PER_WAVE;
    const int node0 = b * MM + row0;
    const float fbase = (float)(b * MM);   // exact: <= 130944 fits fp32

    // branch-free output pointers: 3 stores/lane/row through strided pointers
    //  lanes <32 : pA=src[e], pB=vec[3e+0], pC=vec[3e+1]
    //  lanes >=32: pA=dst[e], pB=weight[e], pC=vec[3e+2]
    float* const vecbase = out + 3 * (size_t)NEDGE;
    const long e0 = (long)node0 * KK + r;
    float* pA = hi ? out + (size_t)NEDGE + e0 : out + e0;
    float* pB = hi ? out + 2 * (size_t)NEDGE + e0 : vecbase + e0 * 3;
    float* pC = hi ? vecbase + e0 * 3 + 2 : vecbase + e0 * 3 + 1;
    const int sA = KK;
    const int sB = hi ? KK : KK * 3;
    const int sC = KK * 3;

#pragma unroll 2
    for (int i = row0; i < row0 + ROWS_PER_WAVE; ++i) {
        const float xi = px[i], yi = py[i], zi = pz[i], qi = sqs[i];

        // ---- candidate keys (fma ok: ulp-level rank flips tolerated) ----
        float dot0 = fmaf(xi, xa, fmaf(yi, ya, zi * za));
        float d20 = fmaxf((qi + qa) - 2.0f * dot0, 0.0f);
        unsigned k0 = (__float_as_uint(d20) & 0xFFFFFF80u) | (unsigned)j0;

        float dot1 = fmaf(xi, xb, fmaf(yi, yb, zi * zb));
        float d21 = fmaxf((qi + qb) - 2.0f * dot1, 0.0f);
        unsigned k1 = (__float_as_uint(d21) & 0xFFFFFF80u) | (unsigned)j1;

        // ---- phase 1: sort the four 32-blocks (lower lanes asc, upper desc) ----
#define P1(S, ST) k0 = cex<ST, p1mask(S, ST)>(k0); k1 = cex<ST, p1mask(S, ST)>(k1);
        P1(2, 1)
        P1(4, 2)  P1(4, 1)
        P1(8, 4)  P1(8, 2)  P1(8, 1)
        P1(16, 8) P1(16, 4) P1(16, 2) P1(16, 1)
        P1(32, 16) P1(32, 8) P1(32, 4) P1(32, 2) P1(32, 1)
#undef P1

        // ---- phase 2: bitonic split across the 32-lane halves ----
        unsigned c  = minxor32(k0);   // smallest 32 of candidates 0..63   (bitonic)
        unsigned c2 = minxor32(k1);   // smallest 32 of candidates 64..127 (bitonic)

        // ---- phase 3: clean c ascending, c2 descending ----
#define P3(ST) c = cex<ST, cleanmask(ST)>(c); c2 = cex<ST, ~cleanmask(ST)>(c2);
        P3(16) P3(8) P3(4) P3(2) P3(1)
#undef P3

        // ---- phase 4: in-lane split of [c asc ; c2 desc] ----
        unsigned m = __builtin_elementwise_min(c, c2);   // smallest 32 overall (bitonic)

        // ---- phase 5: final clean ascending ----
#define P5(ST) m = cex<ST, cleanmask(ST)>(m);
        P5(16) P5(8) P5(4) P5(2) P5(1)
#undef P5

        // ---- epilogue: rank r duplicated across halves; 3 branch-free stores ----
        const bool taken = m < 0x41C80000u;   // d2 < 25.0
        const int j = (int)(m & 127u);
        const int sel = taken ? j : i;

        float dxv = __fsub_rn(px[sel], xi);
        float dyv = __fsub_rn(py[sel], yi);
        float dzv = __fsub_rn(pz[sel], zi);
        float w = (taken && j != i)
                      ? sqrtf(__fadd_rn(__fadd_rn(__fmul_rn(dxv, dxv), __fmul_rn(dyv, dyv)),
                                        __fmul_rn(dzv, dzv)))
                      : 0.0f;

        const float fnode = (float)(b * MM + i);
        const float fsrc = fbase + (float)sel;   // exact integers in fp32

        *pA = hi ? fnode : fsrc;
        *pB = hi ? w : dxv;
        *pC = hi ? dzv : dyv;
        pA += sA; pB += sB; pC += sC;
    }
}

extern "C" void kernel_launch(void* const* d_in, const int* in_sizes, int n_in,
                              void* d_out, int out_size, void* d_ws, size_t ws_size,
                              hipStream_t stream) {
    const float* pos = (const float*)d_in[0];
    float* out = (float*)d_out;
    hipLaunchKernelGGL(knn_edges_kernel, dim3(BB * BPB), dim3(256), 0, stream, pos, out);
}

// Round 7
// 45.201 us; speedup vs baseline: 1.2589x; 1.0828x over previous
//
#include <hip/hip_runtime.h>
#include <stdint.h>

// Problem constants
#define BB 1024
#define MM 128
#define KK 32
#define NEDGE (BB * MM * KK)   // 4194304
#define BPB 4                  // blocks per batch
#define ROWS_PER_WAVE (MM / (4 * BPB))  // 8

typedef unsigned int uint2v __attribute__((ext_vector_type(2)));

// ---- keep-min lane masks (compile-time) ----
// phase 1, k0: lanes 0-31 asc, 32-63 desc (blocks A,B); k1 uses ~p1mask (C desc, D asc)
static constexpr unsigned long long p1mask(int size, int stride) {
    unsigned long long m = 0;
    for (int l = 0; l < 64; ++l) {
        int g = l & 31;
        bool up = (((g & size) == 0) != (l >= 32));
        bool keep = (((g & stride) == 0) == up);
        if (keep) m |= 1ull << l;
    }
    return m;
}
// dual clean: lower half asc, upper half desc
static constexpr unsigned long long dualmask(int stride) {
    unsigned long long m = 0;
    for (int l = 0; l < 64; ++l) {
        int g = l & 31;
        bool km = (l < 32) ? ((g & stride) == 0) : ((g & stride) != 0);
        if (km) m |= 1ull << l;
    }
    return m;
}
// final clean: asc, duplicated halves
static constexpr unsigned long long cleanmask(int stride) {
    unsigned long long m = 0;
    for (int l = 0; l < 64; ++l) {
        int g = l & 31;
        if ((g & stride) == 0) m |= 1ull << l;
    }
    return m;
}

#define DPP1 "quad_perm:[1,0,3,2] row_mask:0xf bank_mask:0xf"
#define DPP2 "quad_perm:[2,3,0,1] row_mask:0xf bank_mask:0xf"
#define DPP8 "row_ror:8 row_mask:0xf bank_mask:0xf"

// ---- fused dual-key DPP compare-exchange (6 VALU for both keys) ----
// k0 keeps p1mask(S,ST); k1 keeps ~p1mask(S,ST). DPP read-after-write hazard
// covered by the k0/k1 alternation inside the block; NOPSTR guards the entry.
#define CEX2_DPP(DPPSTR, NOPSTR, S, ST)                                      \
  { constexpr unsigned long long M0c = p1mask(S, ST);                        \
    constexpr unsigned long long M1c = ~p1mask(S, ST);                       \
    unsigned mn0, mx0, mn1, mx1, r0, r1;                                     \
    asm(NOPSTR                                                               \
        "v_min_u32_dpp %0, %6, %6 " DPPSTR "\n\t"                            \
        "v_max_u32_dpp %1, %6, %6 " DPPSTR "\n\t"                            \
        "v_min_u32_dpp %2, %7, %7 " DPPSTR "\n\t"                            \
        "v_max_u32_dpp %3, %7, %7 " DPPSTR "\n\t"                            \
        "v_cndmask_b32 %4, %1, %0, %8\n\t"                                   \
        "v_cndmask_b32 %5, %3, %2, %9"                                       \
        : "=&v"(mn0), "=&v"(mx0), "=&v"(mn1), "=&v"(mx1), "=&v"(r0), "=&v"(r1)\
        : "v"(k0), "v"(k1), "s"(M0c), "s"(M1c));                             \
    k0 = r0; k1 = r1; }

// dual-key swizzle compare-exchange (partner fetch on LDS pipe)
#define CEX2_SW(ST, S)                                                       \
  { constexpr unsigned long long M0c = p1mask(S, ST);                        \
    constexpr unsigned long long M1c = ~p1mask(S, ST);                       \
    unsigned p0 = (unsigned)__builtin_amdgcn_ds_swizzle((int)k0, ((ST) << 10) | 0x1F); \
    unsigned p1 = (unsigned)__builtin_amdgcn_ds_swizzle((int)k1, ((ST) << 10) | 0x1F); \
    unsigned mn0 = __builtin_elementwise_min(k0, p0);                        \
    unsigned mx0 = __builtin_elementwise_max(k0, p0);                        \
    unsigned mn1 = __builtin_elementwise_min(k1, p1);                        \
    unsigned mx1 = __builtin_elementwise_max(k1, p1);                        \
    unsigned r0, r1;                                                         \
    asm("v_cndmask_b32 %0, %1, %2, %3" : "=v"(r0) : "v"(mx0), "v"(mn0), "s"(M0c)); \
    asm("v_cndmask_b32 %0, %1, %2, %3" : "=v"(r1) : "v"(mx1), "v"(mn1), "s"(M1c)); \
    k0 = r0; k1 = r1; }

// single-stream cex (dual-clean / final clean): s_nop-guarded DPP or swizzle
template<int ST, unsigned long long MASK>
static __device__ __forceinline__ unsigned cex1(unsigned k) {
    unsigned mn, mx, r;
    if constexpr (ST == 1) {
        asm("s_nop 1\n\t"
            "v_min_u32_dpp %0, %2, %2 " DPP1 "\n\t"
            "v_max_u32_dpp %1, %2, %2 " DPP1
            : "=&v"(mn), "=&v"(mx) : "v"(k));
    } else if constexpr (ST == 2) {
        asm("s_nop 1\n\t"
            "v_min_u32_dpp %0, %2, %2 " DPP2 "\n\t"
            "v_max_u32_dpp %1, %2, %2 " DPP2
            : "=&v"(mn), "=&v"(mx) : "v"(k));
    } else if constexpr (ST == 8) {
        asm("s_nop 1\n\t"
            "v_min_u32_dpp %0, %2, %2 " DPP8 "\n\t"
            "v_max_u32_dpp %1, %2, %2 " DPP8
            : "=&v"(mn), "=&v"(mx) : "v"(k));
    } else {
        unsigned p = (unsigned)__builtin_amdgcn_ds_swizzle((int)k, (ST << 10) | 0x1F);
        mn = __builtin_elementwise_min(k, p);
        mx = __builtin_elementwise_max(k, p);
    }
    asm("v_cndmask_b32 %0, %1, %2, %3" : "=v"(r) : "v"(mx), "v"(mn), "s"(MASK));
    return r;
}

// min over {v[l], v[l^32]} — bitonic split across the 32-lane halves
static __device__ __forceinline__ unsigned minxor32(unsigned k) {
#if __has_builtin(__builtin_amdgcn_permlane32_swap)
    uint2v s = __builtin_amdgcn_permlane32_swap(k, k, false, false);
    return __builtin_elementwise_min(s.x, s.y);
#else
    unsigned p = (unsigned)__shfl_xor((int)k, 32, 64);
    return __builtin_elementwise_min(k, p);
#endif
}

// grid = BB*BPB blocks of 256 threads; each wave handles 8 rows.
// Per row: 128 candidates (2/lane), key = (f32bits(max(d2,0)) & ~0x7F) | j.
// Network: sort A asc|B desc (k0) and C desc|D asc (k1); min(k0,k1) is a
// shuffle-free bitonic split; dual-clean; permlane split; final clean.
__global__ __launch_bounds__(256, 4) void knn_edges_kernel(const float* __restrict__ pos,
                                                           float* __restrict__ out) {
    __shared__ float px[MM], py[MM], pz[MM], sqs[MM];
    const int blk = blockIdx.x;
    const int b = blk >> 2;            // blk / BPB
    const int sub = blk & (BPB - 1);
    const int tid = threadIdx.x;

    if (tid < MM) {
        const float* p = pos + (size_t)(b * MM + tid) * 3;
        float x = p[0], y = p[1], z = p[2];
        px[tid] = x; py[tid] = y; pz[tid] = z;
        sqs[tid] = __fadd_rn(__fadd_rn(__fmul_rn(x, x), __fmul_rn(y, y)), __fmul_rn(z, z));
    }
    __syncthreads();

    const int wave = tid >> 6;
    const int lane = tid & 63;
    const int r = lane & 31;
    const bool hi = lane >= 32;

    // per-lane candidate coordinates, hoisted across the row loop
    const int j0 = lane, j1 = lane + 64;
    const float xa = px[j0], ya = py[j0], za = pz[j0], qa = sqs[j0];
    const float xb = px[j1], yb = py[j1], zb = pz[j1], qb = sqs[j1];

    const int row0 = sub * (MM / BPB) + wave * ROWS_PER_WAVE;
    const int node0 = b * MM + row0;
    const float fbase = (float)(b * MM);   // exact in fp32

    // output streams (3 stores/lane/row):
    //  lanes <32 : pA=src (KK), pB=vec.x (3KK), pC=vec.y (3KK)
    //  lanes >=32: pA=dst (KK), pB=vec.z (3KK), pC=weight (KK)
    float* const vecbase = out + 3 * (size_t)NEDGE;
    const long e0 = (long)node0 * KK + r;
    float* pA = hi ? out + (size_t)NEDGE + e0 : out + e0;
    float* pB = vecbase + e0 * 3 + (hi ? 2 : 0);
    float* pC = hi ? out + 2 * (size_t)NEDGE + e0 : vecbase + e0 * 3 + 1;
    const int sC = hi ? KK : KK * 3;

    float fnode = (float)node0;

#pragma unroll 2
    for (int i = row0; i < row0 + ROWS_PER_WAVE; ++i) {
        const float xi = px[i], yi = py[i], zi = pz[i], qi = sqs[i];

        // ---- candidate keys ----
        float dot0 = fmaf(xi, xa, fmaf(yi, ya, zi * za));
        float d20 = fmaxf((qi + qa) - 2.0f * dot0, 0.0f);
        unsigned k0 = (__float_as_uint(d20) & 0xFFFFFF80u) | (unsigned)j0;

        float dot1 = fmaf(xi, xb, fmaf(yi, yb, zi * zb));
        float d21 = fmaxf((qi + qb) - 2.0f * dot1, 0.0f);
        unsigned k1 = (__float_as_uint(d21) & 0xFFFFFF80u) | (unsigned)j1;

        // ---- phase 1: sort four 32-blocks; k0: A asc|B desc, k1: C desc|D asc
        CEX2_DPP(DPP1, "s_nop 1\n\t", 2, 1)
        CEX2_DPP(DPP2, "",            4, 2)
        CEX2_DPP(DPP1, "",            4, 1)
        CEX2_SW(4,                    8)
        CEX2_DPP(DPP2, "s_nop 1\n\t", 8, 2)
        CEX2_DPP(DPP1, "",            8, 1)
        CEX2_DPP(DPP8, "",            16, 8)
        CEX2_SW(4,                    16)
        CEX2_DPP(DPP2, "s_nop 1\n\t", 16, 2)
        CEX2_DPP(DPP1, "",            16, 1)
        CEX2_SW(16,                   32)
        CEX2_DPP(DPP8, "s_nop 1\n\t", 32, 8)
        CEX2_SW(4,                    32)
        CEX2_DPP(DPP2, "s_nop 1\n\t", 32, 2)
        CEX2_DPP(DPP1, "",            32, 1)

        // ---- merge 1: shuffle-free bitonic split (A∪C | B∪D) ----
        unsigned c = __builtin_elementwise_min(k0, k1);

        // ---- dual clean: lower 32 asc, upper 32 desc ----
        c = cex1<16, dualmask(16)>(c);
        c = cex1<8,  dualmask(8)>(c);
        c = cex1<4,  dualmask(4)>(c);
        c = cex1<2,  dualmask(2)>(c);
        c = cex1<1,  dualmask(1)>(c);

        // ---- merge 2: split across halves (duplicated result) ----
        unsigned m = minxor32(c);

        // ---- final clean ascending ----
        m = cex1<16, cleanmask(16)>(m);
        m = cex1<8,  cleanmask(8)>(m);
        m = cex1<4,  cleanmask(4)>(m);
        m = cex1<2,  cleanmask(2)>(m);
        m = cex1<1,  cleanmask(1)>(m);

        // ---- epilogue: rank r duplicated across halves; 3 stores/lane ----
        const bool taken = m < 0x41C80000u;   // d2 < 25.0
        const int j = (int)(m & 127u);
        const int sel = taken ? j : i;

        float dxv = __fsub_rn(px[sel], xi);
        float dyv = __fsub_rn(py[sel], yi);
        float dzv = __fsub_rn(pz[sel], zi);
        // w = |vec|; sqrt(0)=0 covers both !taken and self, no conditional
        float w = sqrtf(fmaf(dzv, dzv, fmaf(dyv, dyv, dxv * dxv)));

        const float fsrc = fbase + (float)sel;   // exact integer in fp32

        *pA = hi ? fnode : fsrc;
        *pB = hi ? dzv : dxv;
        *pC = hi ? w : dyv;
        pA += KK; pB += KK * 3; pC += sC;
        fnode += 1.0f;
    }
}

extern "C" void kernel_launch(void* const* d_in, const int* in_sizes, int n_in,
                              void* d_out, int out_size, void* d_ws, size_t ws_size,
                              hipStream_t stream) {
    const float* pos = (const float*)d_in[0];
    float* out = (float*)d_out;
    hipLaunchKernelGGL(knn_edges_kernel, dim3(BB * BPB), dim3(256), 0, stream, pos, out);
}